// Round 5
// baseline (402.390 us; speedup 1.0000x reference)
//
#include <hip/hip_runtime.h>
#include <hip/hip_bf16.h>
#include <math.h>

// Model: out[b,p,c] = sum_l Kmat[p,l] * x[b,l,c] + bias[p]
// Kmat = Weff_s @ D + (Weff_t - Weff_s) @ (D@T),  Weff = (W @ M)/512
// RESOLVED (r0-r4 evidence): inputs are f32, OUTPUT IS F32 (writing bf16 into
// the f32 out buffer produced the deterministic 0.1606 signature; r3's NaN was
// f32-read-as-bf16). This round: f32 stores + the verified MFMA GEMM.

#define BATCH 64
#define SEQ 1024
#define CH 512
#define PRED 720
#define INV_SQRT2 0.70710678118654752440f

typedef __attribute__((ext_vector_type(4))) float floatx4;
typedef __attribute__((ext_vector_type(8))) short bf16x8;

// ---- workspace layout (bytes) — TOTAL 5.6 MB ----
#define KBF_OFF   0ull          // bf16 Kmat[768][1024]     = 1,572,864 B
#define BIAS_OFF  1572864ull    // f32 bias[768]            =     3,072 B
#define MW_OFF    1575936ull    // f32 Mw[512][512] (M/512) = 1,048,576 B
#define WEFFS_OFF 2624512ull    // f32 WeffS[720][512]      = 1,474,560 B
#define WEFFT_OFF 4099072ull    // f32 WeffT[720][512]      = 1,474,560 B

// ---------------- DCT basis (scale & /512 folded in) ----------------
__global__ void build_M(float* __restrict__ Mw) {
    int idx = blockIdx.x * 256 + threadIdx.x;   // 512*512
    int k = idx >> 9, n = idx & 511;
    // angle = pi*(n+0.5)*k/512 = pi*((2n+1)*k mod 2048)/1024 (exact reduction)
    int m = ((2 * n + 1) * k) & 2047;
    float ang = (float)m * (float)(M_PI / 1024.0);
    float scale = (k == 0) ? 0.04419417382415922f /* sqrt(1/512) */
                           : 0.0625f;            /* sqrt(2/512)  */
    Mw[idx] = cosf(ang) * scale * (1.0f / 512.0f);
}

// ---------------- Weff = W @ Mw  (720x512 @ 512x512, f32) ----------------
__global__ void build_weff(const float* __restrict__ Ws_in, const float* __restrict__ Wt_in,
                           const float* __restrict__ Mw,
                           float* __restrict__ outS, float* __restrict__ outT) {
    const float* W = blockIdx.z ? Wt_in : Ws_in;
    float* out     = blockIdx.z ? outT  : outS;
    int n0 = blockIdx.x * 64;   // 8 tiles
    int p0 = blockIdx.y * 16;   // 45 tiles -> 720
    int t  = threadIdx.x;
    int tn = t & 63, tp = t >> 6;
    int pbase = p0 + tp * 4;
    __shared__ float mt[64][64];
    float a0 = 0.f, a1 = 0.f, a2 = 0.f, a3 = 0.f;
    for (int kb = 0; kb < 512; kb += 64) {
        __syncthreads();
        for (int i = 0; i < 16; i++) {
            int idx = t + i * 256;
            mt[idx >> 6][idx & 63] = Mw[(size_t)(kb + (idx >> 6)) * 512 + n0 + (idx & 63)];
        }
        __syncthreads();
        for (int kk = 0; kk < 64; kk++) {
            float m = mt[kk][tn];
            int kg = kb + kk;
            a0 += W[(size_t)(pbase + 0) * 512 + kg] * m;
            a1 += W[(size_t)(pbase + 1) * 512 + kg] * m;
            a2 += W[(size_t)(pbase + 2) * 512 + kg] * m;
            a3 += W[(size_t)(pbase + 3) * 512 + kg] * m;
        }
    }
    out[(size_t)(pbase + 0) * 512 + n0 + tn] = a0;
    out[(size_t)(pbase + 1) * 512 + n0 + tn] = a1;
    out[(size_t)(pbase + 2) * 512 + n0 + tn] = a2;
    out[(size_t)(pbase + 3) * 512 + n0 + tn] = a3;
}

// ---------------- Kmat build (banded D@T analytic) ----------------
// cnt(j,l) = #{d in [-12,12] : clamp(j+d,0,1023) == l}
__device__ __forceinline__ int tcnt(int j, int l) {
    if (l == 0)    return max(0, 13 - j);
    if (l == 1023) return max(0, j - 1010);
    int d = l - j; if (d < 0) d = -d;
    return (d <= 12) ? 1 : 0;
}

__global__ void build_kmat(const float* __restrict__ Ws, const float* __restrict__ Wt,
                           const float* __restrict__ bs, const float* __restrict__ bt,
                           __hip_bfloat16* __restrict__ Kbf, float* __restrict__ bias) {
    int idx = blockIdx.x * 256 + threadIdx.x;   // 768*1024
    int p = idx >> 10, l = idx & 1023;
    if (p >= PRED) { Kbf[idx] = __float2bfloat16(0.0f); return; }  // zero pad rows
    if (l == 0) bias[p] = bs[p] + bt[p];
    float v = INV_SQRT2 * Ws[(size_t)p * 512 + (l >> 1)];   // Weff_s @ D term
    int jlo = max(0, l - 12), jhi = min(1023, l + 12);
    float acc = 0.f;
    for (int n = (jlo >> 1); n <= (jhi >> 1); n++) {
        int c = tcnt(2 * n, l) + tcnt(2 * n + 1, l);
        if (c) acc += (Wt[(size_t)p * 512 + n] - Ws[(size_t)p * 512 + n]) * (float)c;
    }
    v += acc * (INV_SQRT2 / 25.0f);
    Kbf[idx] = __float2bfloat16(v);
}

// ---------------- main GEMM: out[b,p,c] = K[p,:] . x[b,:,c] + bias[p] ----------------
// A (Kmat bf16, k-major) staged via global_load_lds(16B) -> ds_read_b128 (m97).
// B read directly from x[b][l][c] f32 (lanes 0..15 -> 64B coalesced segments),
// cvt->bf16 in-register. Output stored as F32.
__device__ __forceinline__ void async_ld16(const void* g, void* l) {
    __builtin_amdgcn_global_load_lds((const __attribute__((address_space(1))) void*)g,
                                     (__attribute__((address_space(3))) void*)l, 16, 0, 0);
}

__device__ __forceinline__ short f2bf(float f) {
    __hip_bfloat16 h = __float2bfloat16(f);
    return *reinterpret_cast<short*>(&h);
}

__global__ void __launch_bounds__(256) gemm_main(
    const short* __restrict__ Kbf, const float* __restrict__ x,
    const float* __restrict__ bias, float* __restrict__ out) {
    __shared__ __align__(16) short ldsA[128 * 32];   // 8 KB
    int t = threadIdx.x;
    int wave = t >> 6, lane = t & 63;
    int mt = blockIdx.x % 6, nt = blockIdx.x / 6;   // 6 m-tiles (768), 4 n-tiles (512)
    int b  = blockIdx.y;
    int wm = wave >> 1, wn = wave & 1;              // 2x2 waves of 64x64
    const short* Ag = Kbf + (size_t)mt * 128 * 1024;
    const float* xb = x + (size_t)b * SEQ * CH;
    int lm = lane & 15, kq = lane >> 4;
    int cj[4];
    for (int j = 0; j < 4; j++) cj[j] = nt * 128 + wn * 64 + j * 16 + lm;

    floatx4 acc[4][4];
    for (int i = 0; i < 4; i++)
        for (int j = 0; j < 4; j++)
            acc[i][j] = (floatx4){0.f, 0.f, 0.f, 0.f};

    for (int k0 = 0; k0 < 1024; k0 += 32) {
        // stage A tile (128 rows x 32 k): chunk q=rdi*256+t -> [row=q>>2][ko=(q&3)*8]
        for (int rdi = 0; rdi < 2; rdi++) {
            int q = rdi * 256 + t;
            int row = q >> 2, ko = (q & 3) * 8;
            async_ld16(Ag + (size_t)row * 1024 + k0 + ko,
                       (char*)ldsA + rdi * 4096 + wave * 1024);
        }
        // B frags: direct f32 loads, cvt->bf16: B[k=kq*8+i][n=cj[j]]
        bf16x8 bfrag[4];
        int krow = k0 + kq * 8;
#pragma unroll
        for (int j = 0; j < 4; j++) {
            const float* xc = xb + (size_t)krow * CH + cj[j];
            bf16x8 bv;
#pragma unroll
            for (int i = 0; i < 8; i++) bv[i] = f2bf(xc[(size_t)i * CH]);
            bfrag[j] = bv;
        }
        __syncthreads();
        bf16x8 af[4];
        for (int i = 0; i < 4; i++)
            af[i] = *(const bf16x8*)&ldsA[(wm * 64 + i * 16 + lm) * 32 + kq * 8];
        for (int i = 0; i < 4; i++)
            for (int j = 0; j < 4; j++)
                acc[i][j] = __builtin_amdgcn_mfma_f32_16x16x32_bf16(af[i], bfrag[j], acc[i][j], 0, 0, 0);
        __syncthreads();
    }

    // epilogue: D[row=(lane>>4)*4+r][col=lane&15], +bias, F32 store
    int p0 = mt * 128 + wm * 64;
    size_t outb = (size_t)b * PRED * CH;
    for (int i = 0; i < 4; i++) {
        for (int r = 0; r < 4; r++) {
            int p = p0 + i * 16 + kq * 4 + r;
            if (p < PRED) {
                float bv = bias[p];
                for (int j = 0; j < 4; j++) {
                    out[outb + (size_t)p * CH + cj[j]] = acc[i][j][r] + bv;
                }
            }
        }
    }
}

extern "C" void kernel_launch(void* const* d_in, const int* in_sizes, int n_in,
                              void* d_out, int out_size, void* d_ws, size_t ws_size,
                              hipStream_t stream) {
    // size-based remap (robust to order); fallback to dict order
    const float* xp = nullptr; const float* wp[2] = {nullptr, nullptr};
    const float* bp[2] = {nullptr, nullptr};
    int wn = 0, bn = 0;
    for (int i = 0; i < n_in; i++) {
        if (in_sizes[i] == 33554432) xp = (const float*)d_in[i];
        else if (in_sizes[i] == 368640 && wn < 2) wp[wn++] = (const float*)d_in[i];
        else if (in_sizes[i] == 720 && bn < 2) bp[bn++] = (const float*)d_in[i];
    }
    if (!xp || wn != 2 || bn != 2) {
        xp = (const float*)d_in[0]; wp[0] = (const float*)d_in[1];
        bp[0] = (const float*)d_in[2]; wp[1] = (const float*)d_in[3];
        bp[1] = (const float*)d_in[4];
    }
    float* out = (float*)d_out;   // F32 output (r0-r4 deduction)

    char* ws = (char*)d_ws;   // 5.6 MB
    __hip_bfloat16* Kbf = (__hip_bfloat16*)(ws + KBF_OFF);
    float* bias  = (float*)(ws + BIAS_OFF);
    float* Mw    = (float*)(ws + MW_OFF);
    float* WeffS = (float*)(ws + WEFFS_OFF);
    float* WeffT = (float*)(ws + WEFFT_OFF);

    build_M<<<1024, 256, 0, stream>>>(Mw);
    build_weff<<<dim3(8, 45, 2), 256, 0, stream>>>(wp[0], wp[1], Mw, WeffS, WeffT);
    build_kmat<<<3072, 256, 0, stream>>>(WeffS, WeffT, bp[0], bp[1], Kbf, bias);
    gemm_main<<<dim3(24, 64), 256, 0, stream>>>((const short*)Kbf, xp, bias, out);
}